// Round 5
// baseline (454.702 us; speedup 1.0000x reference)
//
#include <hip/hip_runtime.h>

// 2-layer LSTM (H=50) + FC head. Transposed-MFMA fp16, cross-layer pipelined.
// R18 = BARRIER-FREE PRODUCER/CONSUMER FLAG SYNC (the convoy breaker):
//   R13/R14/R17 all pin at ~1657 cy/phase regardless of -100..-170 cy issue
//   cuts; R15 shows a 2nd independent block barely compresses (1537). Theory:
//   the 16-wave barrier convoy serializes pipe bursts (LDS 30% + MFMA 20% +
//   VALU 56% ~= 106% of phase). Fix: two decoupled teams with LDS counters:
//     L1 team (w7..15, 9 waves, prio 1): owns the serial h1 recurrence.
//     L2 team (w0..6, 7 waves): consumes h1 with 1..3-phase lag.
//   Quad-buffered h1/h2 push WAR to distance 3. Waits (proved safe below):
//     L1@p: h1c >= 9p (RAW h1[p-1])  && h2c >= 7(p-3) (WAR: L2 past p-3)
//     L2@q: h1c >= 9q (RAW h1[q-1])  && h2c >= 7(q-1) (RAW h2[q-2])
//   Safety: phase t reads buf[t&3], writes buf[(t+1)&3]. L1@p writes
//   h1f[(p+1)&3]; L2 reader at q collides iff q ≡ p+1 (mod 4), q<p -> q=p-3;
//   excluded by h2c >= 7(p-3) (L2 finished p-3). Intra-team spread <= 1 phase
//   (team counters are all-to-all within team). No deadlock: L1 blocked needs
//   L2 <= p-4; L2 blocked needs L1 < q <= p -> contradiction.
//   Producer: writes -> s_waitcnt lgkmcnt(0) -> 1 ds_add per wave (lane 0).
//   Consumer: volatile spin -> sched_barrier(0) + "memory" before reads.
// Cell: R14 shared-reciprocal (7 trans). Weights in regs, h in LDS frag
// layout; gate rows permuted p=4j+g; x + biases ride dead K-lanes.

#define HID 50
#define SEQ 512
#define NB 16
#define NTHREADS 1024     // 16 waves: 7 L2 + 9 L1
#define XP 516            // xs row stride (floats)

typedef _Float16 f16x8 __attribute__((ext_vector_type(8)));
typedef float    f32x4 __attribute__((ext_vector_type(4)));

#define LOG2E 1.44269504f

__device__ __forceinline__ float lstm_cell(const f32x4 g, float& c) {
    const float ei = __builtin_amdgcn_exp2f(g[0]);
    const float ef = __builtin_amdgcn_exp2f(g[1]);
    const float eg = __builtin_amdgcn_exp2f(g[2]);
    const float eo = __builtin_amdgcn_exp2f(g[3]);
    const float A  = ei + 1.0f;
    const float F  = ef + 1.0f;
    const float G  = eg + 1.0f;
    const float AG  = A * G;
    const float den = AG * F;
    const float num = __builtin_fmaf(eg - 1.0f, F, c * AG);
    c = num * __builtin_amdgcn_rcpf(den);           // c' = f*c + i*tanh(xg)
    float z = c * (2.0f * LOG2E);
    z = __builtin_fminf(z, 100.0f);
    const float ec = __builtin_amdgcn_exp2f(z);
    return (ec - 1.0f) *
           __builtin_amdgcn_rcpf((eo + 1.0f) * (ec + 1.0f));  // o*tanh(c')
}

// spin until *c >= tgt; fence so dependent LDS reads can't float above
__device__ __forceinline__ void waitge(volatile int* c, int tgt) {
    if (tgt > 0) {
        while (*c < tgt) { }
        __builtin_amdgcn_sched_barrier(0);
        asm volatile("" ::: "memory");
    }
}

// h LDS layout: 16B chunk (kt*4+qh)*16 + m holds h[m][k = kt*32+qh*8+0..7].
// Reader (lane m=l15, quad qq, k-chunk kt) reads chunk (kt*4+qq)*16+m.
// Writer of h[m][j]: chunk ((j>>5)*4+((j>>3)&3))*16 + m, half j&7.
// j=50 -> chunk 96+m half 2 (x rides here), j=51 -> chunk 96+m half 3 (1.0).

__global__ __launch_bounds__(NTHREADS)
void lstm2_fc_v18(const float* __restrict__ x,
                  const float* __restrict__ w_ih0,
                  const float* __restrict__ w_hh0,
                  const float* __restrict__ b_ih0,
                  const float* __restrict__ b_hh0,
                  const float* __restrict__ w_ih1,
                  const float* __restrict__ w_hh1,
                  const float* __restrict__ b_ih1,
                  const float* __restrict__ b_hh1,
                  const float* __restrict__ fc_w,
                  const float* __restrict__ fc_b,
                  float* __restrict__ out)
{
    __shared__ float xs[NB * XP];        // 33 KB
    __shared__ f16x8 h1f[4][128];        //  8 KB  h1 quad-buffered
    __shared__ f16x8 h2f[4][128];        //  8 KB  h2 quad-buffered
    __shared__ int   cnt[32];            // cnt[0]=h1c, cnt[16]=h2c

    const int tid = threadIdx.x;
    const int b0  = blockIdx.x * NB;
    const int w   = tid >> 6;
    const int l15 = tid & 15;
    const int qq  = (tid >> 4) & 3;

    // ---- team / task tables (wave-uniform) ----
    // L2 team: w0..5 tiles {2w,2w+1}, w6 {12}
    // L1 team: w7..10 tiles {2(w-7),2(w-7)+1}, w11..15 {w-3} (w15 = tile 12)
    const bool isL2w = (w <= 6);
    const int nL1 = isL2w ? 0 : ((w <= 10) ? 2 : 1);
    const int nL2 = isL2w ? ((w <= 5) ? 2 : 1) : 0;
    int tL1[2], tL2[2];
    tL1[0] = (!isL2w) ? ((w <= 10) ? 2 * (w - 7) : (w - 3)) : 0;
    tL1[1] = (!isL2w && w <= 10) ? 2 * (w - 7) + 1 : 0;
    tL2[0] = isL2w ? ((w <= 5) ? 2 * w : 12) : 0;
    tL2[1] = (isL2w && w <= 5) ? 2 * w + 1 : 0;

    if (!isL2w) __builtin_amdgcn_s_setprio(1);   // h1 chain = critical path

    // ---- stage x into LDS (coalesced float4) ----
    for (int idx = tid; idx < NB * 128; idx += NTHREADS) {
        const int b  = idx >> 7;
        const int t4 = idx & 127;
        *(float4*)&xs[b * XP + t4 * 4] =
            *(const float4*)&x[(size_t)(b0 + b) * SEQ + t4 * 4];
    }
    if (tid < NB) {
        const float4 z = {0.f, 0.f, 0.f, 0.f};
        *(float4*)&xs[tid * XP + 512] = z;
    }
    // ---- zero all 8 h buffers (1024 chunks / 1024 threads) ----
    {
        f16x8 z = {};
        if (tid < 512) h1f[tid >> 7][tid & 127] = z;
        else           h2f[(tid >> 7) - 4][tid & 127] = z;
    }
    if (tid == 0) { cnt[0] = 0; cnt[16] = 0; }

    // ---- load weight A-fragments (one-time), gate rows permuted + SCALED ----
    f16x8 wH0[2][2], wI1[2][2], wH1[2][2];
#pragma unroll
    for (int s = 0; s < 2; ++s) {
        const int  p1  = tL1[s] * 16 + l15;
        const bool ok1 = (s < nL1) && (p1 < 4 * HID);
        const int  n1  = ok1 ? ((p1 & 3) * HID + (p1 >> 2)) : 0;
        const float s1 = ((p1 & 3) == 2) ? (2.0f * LOG2E) : -LOG2E;
        const int  p2  = tL2[s] * 16 + l15;
        const bool ok2 = (s < nL2) && (p2 < 4 * HID);
        const int  n2  = ok2 ? ((p2 & 3) * HID + (p2 >> 2)) : 0;
        const float s2 = ((p2 & 3) == 2) ? (2.0f * LOG2E) : -LOG2E;
#pragma unroll
        for (int kt = 0; kt < 2; ++kt) {
            f16x8 f0, f1, f2;
#pragma unroll
            for (int j = 0; j < 8; ++j) {
                const int k = kt * 32 + qq * 8 + j;
                float v0 = 0.0f, v1 = 0.0f, v2 = 0.0f;
                if (ok1) {
                    if (k < HID)          v0 = w_hh0[n1 * HID + k];
                    else if (k == HID)    v0 = w_ih0[n1];
                    else if (k == HID+1)  v0 = b_ih0[n1] + b_hh0[n1];
                    v0 *= s1;
                }
                if (ok2) {
                    if (k < HID)        { v1 = w_ih1[n2 * HID + k];
                                          v2 = w_hh1[n2 * HID + k]; }
                    else if (k == HID+1)  v1 = b_ih1[n2] + b_hh1[n2];
                    v1 *= s2;
                    v2 *= s2;
                }
                f0[j] = (_Float16)v0;
                f1[j] = (_Float16)v1;
                f2[j] = (_Float16)v2;
            }
            wH0[s][kt] = f0;
            wI1[s][kt] = f1;
            wH1[s][kt] = f2;
        }
    }

    // ---- per-lane invariants ----
    int  wOffL1[2], wOffL2[2];
    bool isXT[2];
#pragma unroll
    for (int s = 0; s < 2; ++s) {
        const int ju1 = tL1[s] * 4 + qq;
        wOffL1[s] = ((((ju1 >> 5) * 4) + ((ju1 >> 3) & 3)) * 16 + l15) * 8 + (ju1 & 7);
        const int ju2 = tL2[s] * 4 + qq;
        wOffL2[s] = ((((ju2 >> 5) * 4) + ((ju2 >> 3) & 3)) * 16 + l15) * 8 + (ju2 & 7);
        isXT[s] = (!isL2w) && (s < nL1) && (tL1[s] == 12);
    }
    const int rdo = qq * 16 + l15;
    const float* xrow = xs + l15 * XP;
    const f32x4 z4 = {0.f, 0.f, 0.f, 0.f};

    float c1[2] = {0.f, 0.f}, c2[2] = {0.f, 0.f};

    __syncthreads();   // zeros + xs + cnt visible

    // ---- seed specials: h1f[0] k=50 = x[m][0] (from GLOBAL x, no xs dep);
    //      k=51 = 1.0 in ALL FOUR buffers (1.0 lane never written in-loop) ----
    if (tid < NB) {
        _Float16* e0 = (_Float16*)&h1f[0][96 + tid];
        e0[2] = (_Float16)x[(size_t)(b0 + tid) * SEQ];
        e0[3] = (_Float16)1.0f;
        ((_Float16*)&h1f[1][96 + tid])[3] = (_Float16)1.0f;
        ((_Float16*)&h1f[2][96 + tid])[3] = (_Float16)1.0f;
        ((_Float16*)&h1f[3][96 + tid])[3] = (_Float16)1.0f;
    }
    __syncthreads();   // the LAST barrier in the kernel

    volatile int* h1c = (volatile int*)&cnt[0];
    volatile int* h2c = (volatile int*)&cnt[16];
    const bool bumper = ((tid & 63) == 0);

    if (!isL2w) {
        // =================== L1 team: phases p = 0..511 ===================
#pragma unroll 4
        for (int p = 0; p <= 511; ++p) {
            waitge(h1c, 9 * p);              // RAW: h1[p-1] complete
            waitge(h2c, 7 * (p - 3));        // WAR: L2 past phase p-3
            const f16x8* h1o = h1f[p & 3];
            f16x8*       h1n = (f16x8*)h1f[(p + 1) & 3];
            const f16x8 hb0 = h1o[rdo];
            const f16x8 hb1 = h1o[64 + rdo];
#pragma unroll
            for (int s = 0; s < 2; ++s) if (s < nL1) {
                f32x4 acc;
                acc = __builtin_amdgcn_mfma_f32_16x16x32_f16(wH0[s][0], hb0, z4,  0, 0, 0);
                acc = __builtin_amdgcn_mfma_f32_16x16x32_f16(wH0[s][1], hb1, acc, 0, 0, 0);
                const _Float16 hw = (_Float16)lstm_cell(acc, c1[s]);
                if (!isXT[s]) {
                    ((_Float16*)h1n)[wOffL1[s]] = hw;
                } else {
                    if (qq < 2)       ((_Float16*)h1n)[wOffL1[s]] = hw;
                    else if (qq == 2) ((_Float16*)h1n)[wOffL1[s]] =
                                          (_Float16)xrow[p + 1];
                    /* qq == 3: the 1.0 lane, pre-seeded in all 4 bufs */
                }
            }
            asm volatile("s_waitcnt lgkmcnt(0)" ::: "memory");
            if (bumper) atomicAdd((int*)&cnt[0], 1);
        }
    } else {
        // =================== L2 team: phases q = 1..512 (computes L2[q-1]) ==
#pragma unroll 4
        for (int q = 1; q <= 512; ++q) {
            waitge(h1c, 9 * q);              // RAW: h1[q-1] complete
            waitge(h2c, 7 * (q - 1));        // RAW: h2[q-2] complete
            const f16x8* h1o = h1f[q & 3];
            const f16x8* h2o = h2f[q & 3];
            f16x8*       h2n = (f16x8*)h2f[(q + 1) & 3];
            const f16x8 hb0 = h1o[rdo];
            const f16x8 hb1 = h1o[64 + rdo];
            const f16x8 sb0 = h2o[rdo];
            const f16x8 sb1 = h2o[64 + rdo];
#pragma unroll
            for (int s = 0; s < 2; ++s) if (s < nL2) {
                f32x4 acc_a, acc_b;
                acc_a = __builtin_amdgcn_mfma_f32_16x16x32_f16(wI1[s][0], hb0, z4,    0, 0, 0);
                acc_a = __builtin_amdgcn_mfma_f32_16x16x32_f16(wI1[s][1], hb1, acc_a, 0, 0, 0);
                acc_b = __builtin_amdgcn_mfma_f32_16x16x32_f16(wH1[s][0], sb0, z4,    0, 0, 0);
                acc_b = __builtin_amdgcn_mfma_f32_16x16x32_f16(wH1[s][1], sb1, acc_b, 0, 0, 0);
                const f32x4 acc = acc_a + acc_b;
                ((_Float16*)h2n)[wOffL2[s]] = (_Float16)lstm_cell(acc, c2[s]);
            }
            asm volatile("s_waitcnt lgkmcnt(0)" ::: "memory");
            if (bumper) atomicAdd((int*)&cnt[16], 1);
        }
    }

    // ============ FC head: out[b] = h2[T-1] . fc_w + fc_b ============
    // h2[511] written at q=512 into h2f[(512+1)&3] = h2f[1].
    if (tid < NB) {                         // lanes of wave 0 (L2 team)
        waitge(h2c, 7 * 512);               // all L2 phases complete
        const int m = tid;
        const _Float16* h2e = (const _Float16*)h2f[1];
        float s = fc_b[0];
        for (int j = 0; j < HID; ++j) {
            const int chunk = (((j >> 5) * 4) + ((j >> 3) & 3)) * 16 + m;
            s += fc_w[j] * (float)h2e[chunk * 8 + (j & 7)];
        }
        out[b0 + m] = s;
    }
}

extern "C" void kernel_launch(void* const* d_in, const int* in_sizes, int n_in,
                              void* d_out, int out_size, void* d_ws, size_t ws_size,
                              hipStream_t stream) {
    const float* x     = (const float*)d_in[0];
    const float* w_ih0 = (const float*)d_in[1];
    const float* w_hh0 = (const float*)d_in[2];
    const float* b_ih0 = (const float*)d_in[3];
    const float* b_hh0 = (const float*)d_in[4];
    const float* w_ih1 = (const float*)d_in[5];
    const float* w_hh1 = (const float*)d_in[6];
    const float* b_ih1 = (const float*)d_in[7];
    const float* b_hh1 = (const float*)d_in[8];
    const float* fc_w  = (const float*)d_in[9];
    const float* fc_b  = (const float*)d_in[10];
    float* out = (float*)d_out;

    const int B = in_sizes[0] / SEQ;  // 4096

    lstm2_fc_v18<<<B / NB, NTHREADS, 0, stream>>>(
        x, w_ih0, w_hh0, b_ih0, b_hh0, w_ih1, w_hh1, b_ih1, b_hh1, fc_w, fc_b, out);
}